// Round 1
// baseline (9228.342 us; speedup 1.0000x reference)
//
#include <hip/hip_runtime.h>
#include <cmath>

#define NLEV 16
#define TBLSZ 524288
#define TMASK 524287u
#define STR 65          // LDS row stride in floats (pad 64->65 for transpose epilogue)
#define ROWS 291        // max activation dim (fine MLP input)
#define NPB 64          // points per block

struct EncParams { int res[NLEV]; unsigned dense_mask; };

__device__ __forceinline__ float softplus100(float x) {
  float t = 100.0f * x;
  return (fmaxf(t, 0.0f) + log1pf(expf(-fabsf(t)))) * 0.01f;
}

// Wave g computes output dims j = g*64 + k, k = 0..63, for its 64 points (lanes).
// Weights are wave-uniform -> scalar loads; activations read from LDS per-lane.
template<int IN>
__device__ __forceinline__ void gemm_tile(const float* __restrict__ W,
                                          const float* __restrict__ b,
                                          const float* hb, int g, int lane,
                                          float acc[64]) {
  #pragma unroll
  for (int k = 0; k < 64; ++k) acc[k] = b[g * 64 + k];
  const float* wbase = W + (size_t)(g * 64) * IN;
  int i0 = 0;
  #pragma unroll 1
  for (; i0 + 8 <= IN; i0 += 8) {
    float h[8];
    #pragma unroll
    for (int u = 0; u < 8; ++u) h[u] = hb[(i0 + u) * STR + lane];
    #pragma unroll
    for (int k = 0; k < 64; ++k) {
      const float* wr = wbase + k * IN + i0;
      float a = acc[k];
      #pragma unroll
      for (int u = 0; u < 8; ++u) a = fmaf(wr[u], h[u], a);
      acc[k] = a;
    }
  }
  #pragma unroll 1
  for (; i0 < IN; ++i0) {
    float hv = hb[i0 * STR + lane];
    #pragma unroll
    for (int k = 0; k < 64; ++k)
      acc[k] = fmaf(wbase[k * IN + i0], hv, acc[k]);
  }
}

// One extra output row (j = 256), computed redundantly by every thread.
template<int IN>
__device__ __forceinline__ float gemm_extra(const float* __restrict__ W,
                                            const float* hb, int lane, float init) {
  float a = init;
  #pragma unroll 4
  for (int i = 0; i < IN; ++i)
    a = fmaf(W[i], hb[i * STR + lane], a);
  return a;
}

__global__ __launch_bounds__(256, 2)
void fused_ingp(const float* __restrict__ x,
                const float* __restrict__ ctab, const float* __restrict__ cW0, const float* __restrict__ cb0,
                const float* __restrict__ cW1, const float* __restrict__ cb1,
                const float* __restrict__ cW2, const float* __restrict__ cb2,
                const float* __restrict__ ftab, const float* __restrict__ fW0, const float* __restrict__ fb0,
                const float* __restrict__ fW1, const float* __restrict__ fb1,
                const float* __restrict__ fW2, const float* __restrict__ fb2,
                float* __restrict__ out, EncParams ep) {
  __shared__ float hb[ROWS * STR];
  const int tid = threadIdx.x;
  const int lane = tid & 63;
  const int g = __builtin_amdgcn_readfirstlane(tid >> 6);
  const int pbase = blockIdx.x * NPB;
  const int pt = pbase + lane;

  // ------------- hash encode: 4 levels per wave, both tables share idx/weights -------------
  const float* xp = x + (size_t)3 * pt;
  const float x0 = xp[0], x1 = xp[1], x2 = xp[2];
  const float q0 = fminf(fmaxf((x0 / 1.5f + 1.0f) * 0.5f, 0.0f), 1.0f);
  const float q1 = fminf(fmaxf((x1 / 1.5f + 1.0f) * 0.5f, 0.0f), 1.0f);
  const float q2 = fminf(fmaxf((x2 / 1.5f + 1.0f) * 0.5f, 0.0f), 1.0f);

  if (g == 0) {
    hb[0 * STR + lane] = x0; hb[1 * STR + lane] = x1; hb[2 * STR + lane] = x2;
    hb[288 * STR + lane] = x0; hb[289 * STR + lane] = x1; hb[290 * STR + lane] = x2;
  }

  #pragma unroll
  for (int il = 0; il < 4; ++il) {
    const int l = g * 4 + il;
    const int res = ep.res[l];
    const bool dense = (ep.dense_mask >> l) & 1;
    const float rf = (float)(res - 1);
    const float px = q0 * rf, py = q1 * rf, pz = q2 * rf;
    const int ix = (int)floorf(px), iy = (int)floorf(py), iz = (int)floorf(pz);
    const float wx = px - (float)ix, wy = py - (float)iy, wz = pz - (float)iz;
    float ca0 = 0.f, ca1 = 0.f, fa0 = 0.f, fa1 = 0.f;
    const float* ct = ctab + (size_t)l * TBLSZ * 2;
    const float* ft = ftab + (size_t)l * TBLSZ * 2;
    #pragma unroll
    for (int c = 0; c < 8; ++c) {
      const int ox = c & 1, oy = (c >> 1) & 1, oz = (c >> 2) & 1;
      const int cx = min(ix + ox, res), cy = min(iy + oy, res), cz = min(iz + oz, res);
      unsigned idx;
      if (dense) idx = (unsigned)(cx + (res + 1) * (cy + (res + 1) * cz));
      else idx = (((unsigned)cx) ^ ((unsigned)cy * 2654435761u) ^ ((unsigned)cz * 805459861u)) & TMASK;
      const float wc = (ox ? wx : 1.0f - wx) * (oy ? wy : 1.0f - wy) * (oz ? wz : 1.0f - wz);
      const float2 cv = *(const float2*)(ct + (size_t)idx * 2);
      const float2 fv = *(const float2*)(ft + (size_t)idx * 2);
      ca0 = fmaf(wc, cv.x, ca0); ca1 = fmaf(wc, cv.y, ca1);
      fa0 = fmaf(wc, fv.x, fa0); fa1 = fmaf(wc, fv.y, fa1);
    }
    hb[(3 + 2 * l) * STR + lane] = ca0;  // c_feat -> c_in rows 3..34
    hb[(4 + 2 * l) * STR + lane] = ca1;
    hb[(256 + 2 * l) * STR + lane] = fa0; // f_feat stashed in rows 256..287
    hb[(257 + 2 * l) * STR + lane] = fa1;
  }
  __syncthreads();

  float acc[64];

  // ---------------- coarse MLP ----------------
  gemm_tile<35>(cW0, cb0, hb, g, lane, acc);
  __syncthreads();
  #pragma unroll
  for (int k = 0; k < 64; ++k) hb[(g * 64 + k) * STR + lane] = softplus100(acc[k]);
  __syncthreads();

  gemm_tile<256>(cW1, cb1, hb, g, lane, acc);
  __syncthreads();
  #pragma unroll
  for (int k = 0; k < 64; ++k) hb[(g * 64 + k) * STR + lane] = softplus100(acc[k]);
  __syncthreads();

  float ck[64];
  gemm_tile<256>(cW2, cb2, hb, g, lane, ck);
  float c256 = gemm_extra<256>(cW2 + 256 * 256, hb, lane, cb2[256]);
  __syncthreads();

  // ---------------- assemble fine input: [x(0..2) | f_feat(3..34) | c_fv(35..290)] ----------------
  for (int r = g; r < 35; r += 4) {               // copy stash down; reads rows 256+, writes rows 0..34
    const int src = (r < 3) ? (288 + r) : (253 + r);
    hb[r * STR + lane] = hb[src * STR + lane];
  }
  __syncthreads();
  #pragma unroll
  for (int k = 0; k < 64; ++k) {                  // c_fv = c_out[1..256] -> rows 35..290
    if (k > 0 || g > 0) hb[(34 + g * 64 + k) * STR + lane] = ck[k];
  }
  if (g == 0) hb[290 * STR + lane] = c256;
  __syncthreads();

  // ---------------- fine MLP ----------------
  gemm_tile<291>(fW0, fb0, hb, g, lane, acc);
  __syncthreads();
  #pragma unroll
  for (int k = 0; k < 64; ++k) hb[(g * 64 + k) * STR + lane] = softplus100(acc[k]);
  __syncthreads();

  gemm_tile<256>(fW1, fb1, hb, g, lane, acc);
  __syncthreads();
  #pragma unroll
  for (int k = 0; k < 64; ++k) hb[(g * 64 + k) * STR + lane] = softplus100(acc[k]);
  __syncthreads();

  gemm_tile<256>(fW2, fb2, hb, g, lane, acc);
  float f256 = gemm_extra<256>(fW2 + 256 * 256, hb, lane, fb2[256]);
  __syncthreads();

  // ---------------- epilogue: stage c+f sum, transpose via LDS, coalesced store ----------------
  #pragma unroll
  for (int k = 0; k < 64; ++k) hb[(g * 64 + k) * STR + lane] = ck[k] + acc[k];
  if (g == 0) hb[256 * STR + lane] = c256 + f256;
  __syncthreads();

  const size_t obase = (size_t)pbase * 257;
  for (int idx = tid; idx < NPB * 257; idx += 256) {
    const int p = idx / 257;
    const int j = idx - p * 257;
    out[obase + idx] = hb[j * STR + p];
  }
}

extern "C" void kernel_launch(void* const* d_in, const int* in_sizes, int n_in,
                              void* d_out, int out_size, void* d_ws, size_t ws_size,
                              hipStream_t stream) {
  (void)d_ws; (void)ws_size; (void)n_in; (void)out_size;
  // Replicate numpy's RES computation with host libm doubles (discrete hazard at l=15).
  EncParams ep;
  const double sc = std::exp((std::log(2048.0) - std::log(16.0)) / 15.0);
  unsigned dm = 0;
  for (int l = 0; l < NLEV; ++l) {
    const int r = (int)std::ceil(16.0 * std::pow(sc, (double)l));
    ep.res[l] = r;
    const long long rp = (long long)r + 1;
    if (rp * rp * rp <= (long long)TBLSZ) dm |= (1u << l);
  }
  ep.dense_mask = dm;

  const float* X    = (const float*)d_in[0];
  const float* ctab = (const float*)d_in[1];
  const float* cW0  = (const float*)d_in[2];
  const float* cb0  = (const float*)d_in[3];
  const float* cW1  = (const float*)d_in[4];
  const float* cb1  = (const float*)d_in[5];
  const float* cW2  = (const float*)d_in[6];
  const float* cb2  = (const float*)d_in[7];
  const float* ftab = (const float*)d_in[8];
  const float* fW0  = (const float*)d_in[9];
  const float* fb0  = (const float*)d_in[10];
  const float* fW1  = (const float*)d_in[11];
  const float* fb1  = (const float*)d_in[12];
  const float* fW2  = (const float*)d_in[13];
  const float* fb2  = (const float*)d_in[14];

  const int N = in_sizes[0] / 3;
  fused_ingp<<<dim3(N / NPB), dim3(256), 0, stream>>>(
      X, ctab, cW0, cb0, cW1, cb1, cW2, cb2,
      ftab, fW0, fb0, fW1, fb1, fW2, fb2,
      (float*)d_out, ep);
}